// Round 8
// baseline (91.345 us; speedup 1.0000x reference)
//
#include <hip/hip_runtime.h>
#include <stdint.h>

// PROBE ROUND 2: R5 kernel with INTERNAL x4 REP LOOP. Block b, rep r
// processes the samples of block-tile (b + r*grid/4) % grid, so every sample
// is computed exactly 4 times with identical values (deterministic,
// validation-safe, not DCE-able). Constant build runs once per block, body
// runs 4x. Purpose: (1) discriminate body-cycle-bound (dur ~85-105us) vs
// per-block-startup-bound (~55-70) vs launch-floor (~<=45); (2) push the
// kernel above the 39us harness fills so rocprof top-5 finally shows OUR
// counters (VALUBusy / MfmaUtil / DS / occupancy).

typedef __attribute__((ext_vector_type(8))) _Float16 f16x8;
typedef __attribute__((ext_vector_type(4))) float f32x4;
typedef __attribute__((ext_vector_type(2))) float f32x2;
typedef __attribute__((ext_vector_type(4))) unsigned int u32x4;

#define MFMA16(A,B,C) __builtin_amdgcn_mfma_f32_16x16x32_f16((A),(B),(C),0,0,0)

static __device__ __forceinline__ f32x2 pk_fma(f32x2 a, f32x2 b, f32x2 c) {
    f32x2 d;
    asm("v_pk_fma_f32 %0, %1, %2, %3" : "=v"(d) : "v"(a), "v"(b), "v"(c));
    return d;
}
static __device__ __forceinline__ f32x2 pk_mul(f32x2 a, f32x2 b) {
    f32x2 d;
    asm("v_pk_mul_f32 %0, %1, %2" : "=v"(d) : "v"(a), "v"(b));
    return d;
}
static __device__ __forceinline__ unsigned pkmul16(unsigned a, unsigned b) {
    unsigned d;
    asm("v_pk_mul_f16 %0, %1, %2" : "=v"(d) : "v"(a), "v"(b));
    return d;
}
// sum over lanes {l, l^16, l^32, l^48} (result in every lane), pure VALU
static __device__ __forceinline__ float qsum(float v) {
    float a = v, b = v;
    asm("v_permlane16_swap_b32 %0, %1" : "+v"(a), "+v"(b));
    const float s = a + b;
    float c = s, d = s;
    asm("v_permlane32_swap_b32 %0, %1" : "+v"(c), "+v"(d));
    return c + d;
}

__global__ __launch_bounds__(256, 4) void delan_fwd(
    const float* __restrict__ x,
    const float* __restrict__ W1,  const float* __restrict__ b1,
    const float* __restrict__ W1a, const float* __restrict__ b1a,
    const float* __restrict__ W2,  const float* __restrict__ b2,
    const float* __restrict__ W3,  const float* __restrict__ b3,
    const float* __restrict__ W4,  const float* __restrict__ b4,
    float* __restrict__ out, int n_total)
{
    __shared__ _Float16 afrag[2][4][2][64][8];  // 16 KB: [split][htile][khalf][lane][8]
    __shared__ float w0s[64], w1s[64], bs[64];  // W1 SoA + b1
    __shared__ float cst[6][64];                // W2c0,W2c1,W3c0,W3c1,W4,b1a

    const int tid  = threadIdx.x;
    const int lane = tid & 63;
    const int wid  = tid >> 6;
    const int p    = lane & 15;
    const int qrt  = lane >> 4;

    // ---- Block-constant build (once per block) ----
    if (tid < 64) {
        const int k = tid;
        w0s[k] = W1[2*k]; w1s[k] = W1[2*k+1]; bs[k] = b1[k];
        cst[0][k] = W2[k];      cst[1][k] = W2[64 + k];
        cst[2][k] = W3[k];      cst[3][k] = W3[64 + k];
        cst[4][k] = W4[k];      cst[5][k] = b1a[k];
    }
    {
        const int ht = wid;                 // wave wid builds h-tile wid
#pragma unroll
        for (int kh = 0; kh < 2; ++kh) {
            const int row = ht * 16 + p;
            const int kb  = kh * 32 + qrt * 8;
            float wv[8];
            *(float4*)&wv[0] = *(const float4*)(W1a + row * 64 + kb);
            *(float4*)&wv[4] = *(const float4*)(W1a + row * 64 + kb + 4);
            f16x8 hi, lo;
#pragma unroll
            for (int j = 0; j < 8; ++j) {
                const _Float16 h = (_Float16)wv[j];
                hi[j] = h;
                lo[j] = (_Float16)((wv[j] - (float)h) * 4096.0f);
            }
            *(f16x8*)&afrag[0][ht][kh][lane][0] = hi;
            *(f16x8*)&afrag[1][ht][kh][lane][0] = lo;
        }
    }
    __syncthreads();

    const f32x2 c4096  = {4096.0f, 4096.0f};
    const f32x2 cm4096 = {-4096.0f, -4096.0f};
    const int grid  = gridDim.x;
    const int rstep = grid >> 2;

    for (int rep = 0; rep < 4; ++rep) {
        int vb = blockIdx.x + rep * rstep;
        if (vb >= grid) vb -= grid;
        const int s  = vb * 64 + wid * 16 + p;   // this lane's sample
        const int sc = (s < n_total) ? s : (n_total - 1);

        const float2 xa = *(const float2*)(x + 6 * sc);
        const float2 xb = *(const float2*)(x + 6 * sc + 2);
        const float2 xc = *(const float2*)(x + 6 * sc + 4);
        const float x0 = xa.x, x1 = xa.y;
        const float x2 = xb.x, x3 = xb.y;
        const float x4 = xc.x, x5 = xc.y;

        // ---- Phase A: build B-fragments (packed VALU) ----
        const f32x2 q00 = {x0, x0};
        const f32x2 q11 = {x1, x1};
        u32x4 Bhh[2], Bhl[2], Bu0[2], Bu1[2];
#pragma unroll
        for (int kh = 0; kh < 2; ++kh) {
            const int kb = kh * 32 + qrt * 8;
#pragma unroll
            for (int c = 0; c < 4; ++c) {
                const f32x2 w0p = *(const f32x2*)&w0s[kb + 2*c];
                const f32x2 w1p = *(const f32x2*)&w1s[kb + 2*c];
                const f32x2 bp  = *(const f32x2*)&bs [kb + 2*c];
                const f32x2 prep = pk_fma(w0p, q00, pk_fma(w1p, q11, bp));
                const bool pos0 = prep.x > 0.0f;
                const bool pos1 = prep.y > 0.0f;
                const unsigned mlo = pos0 ? 0x00003C00u : 0x0000A11Fu;
                const unsigned mhi = pos1 ? 0x3C000000u : 0xA11F0000u;
                const unsigned drw = mlo | mhi;
                const unsigned p0w = __builtin_bit_cast(unsigned,
                    __builtin_amdgcn_cvt_pkrtz(w0p.x, w0p.y));
                const unsigned p1w = __builtin_bit_cast(unsigned,
                    __builtin_amdgcn_cvt_pkrtz(w1p.x, w1p.y));
                Bu0[kh][c] = pkmul16(p0w, drw);
                Bu1[kh][c] = pkmul16(p1w, drw);
                f32x2 sp;
                sp.x = pos0 ? 1.0f : 0.01f;
                sp.y = pos1 ? 1.0f : 0.01f;
                const f32x2 h1p = pk_mul(prep, sp);
                const auto hhv = __builtin_amdgcn_cvt_pkrtz(h1p.x, h1p.y);
                Bhh[kh][c] = __builtin_bit_cast(unsigned, hhv);
                f32x2 hf;
                hf.x = (float)hhv[0];
                hf.y = (float)hhv[1];
                const f32x2 tt = pk_mul(h1p, c4096);
                const f32x2 rp = pk_fma(hf, cm4096, tt);   // (h1 - hh) * 4096
                Bhl[kh][c] = __builtin_bit_cast(unsigned,
                    __builtin_amdgcn_cvt_pkrtz(rp.x, rp.y));
            }
        }

        // ---- Phase B: MFMA over 4 h-tiles + fused epilogue ----
        float ag0=0.f, ag1=0.f, al0=0.f, al1=0.f, aoo=0.f;
        float ap00=0.f, ap01=0.f, ap10=0.f, ap11=0.f, ar0=0.f, ar1=0.f;
#pragma unroll
        for (int ht = 0; ht < 4; ++ht) {
            const f16x8 Ah0 = *(const f16x8*)&afrag[0][ht][0][lane][0];
            const f16x8 Ah1 = *(const f16x8*)&afrag[0][ht][1][lane][0];
            const f16x8 Al0 = *(const f16x8*)&afrag[1][ht][0][lane][0];
            const f16x8 Al1 = *(const f16x8*)&afrag[1][ht][1][lane][0];
            const f16x8 bh0 = __builtin_bit_cast(f16x8, Bhh[0]);
            const f16x8 bh1 = __builtin_bit_cast(f16x8, Bhh[1]);
            const f16x8 bl0 = __builtin_bit_cast(f16x8, Bhl[0]);
            const f16x8 bl1 = __builtin_bit_cast(f16x8, Bhl[1]);
            const f16x8 bu00 = __builtin_bit_cast(f16x8, Bu0[0]);
            const f16x8 bu01 = __builtin_bit_cast(f16x8, Bu0[1]);
            const f16x8 bu10 = __builtin_bit_cast(f16x8, Bu1[0]);
            const f16x8 bu11 = __builtin_bit_cast(f16x8, Bu1[1]);

            const int hb = ht * 16 + qrt * 4;
            f32x4 Chi = *(const f32x4*)&cst[5][hb];   // init with b1a
            f32x4 Clo = {0.f,0.f,0.f,0.f};
            f32x4 Cz0 = {0.f,0.f,0.f,0.f};
            f32x4 Cz1 = {0.f,0.f,0.f,0.f};
            Chi = MFMA16(Ah0, bh0, Chi);  Chi = MFMA16(Ah1, bh1, Chi);
            Clo = MFMA16(Ah0, bl0, Clo);  Clo = MFMA16(Ah1, bl1, Clo);
            Clo = MFMA16(Al0, bh0, Clo);  Clo = MFMA16(Al1, bh1, Clo);
            Cz0 = MFMA16(Ah0, bu00, Cz0); Cz0 = MFMA16(Ah1, bu01, Cz0);
            Cz1 = MFMA16(Ah0, bu10, Cz1); Cz1 = MFMA16(Ah1, bu11, Cz1);

            const f32x4 w2a  = *(const f32x4*)&cst[0][hb];
            const f32x4 w2b  = *(const f32x4*)&cst[1][hb];
            const f32x4 w3a  = *(const f32x4*)&cst[2][hb];
            const f32x4 w3b  = *(const f32x4*)&cst[3][hb];
            const f32x4 w4v  = *(const f32x4*)&cst[4][hb];
#pragma unroll
            for (int r = 0; r < 4; ++r) {
                const float ah = fmaf(2.44140625e-4f, Clo[r], Chi[r]);
                const bool pos = ah > 0.0f;
                const float h2 = pos ? ah : 0.01f * ah;
                ag0 = fmaf(w2a[r], h2, ag0);   ag1 = fmaf(w2b[r], h2, ag1);
                al0 = fmaf(w3a[r], h2, al0);   al1 = fmaf(w3b[r], h2, al1);
                aoo = fmaf(w4v[r], h2, aoo);
                const float z0 = Cz0[r], z1 = Cz1[r];
                const float d0 = pos ? z0 : -0.01f * z0;
                const float d1 = pos ? z1 : -0.01f * z1;
                ap00 = fmaf(w3a[r], d0, ap00); ap01 = fmaf(w3a[r], d1, ap01);
                ap10 = fmaf(w3b[r], d0, ap10); ap11 = fmaf(w3b[r], d1, ap11);
                ar0  = fmaf(w4v[r], d0, ar0);  ar1  = fmaf(w4v[r], d1, ar1);
            }
        }

        // ---- Reduce over the 4 h-quarters (pure-VALU permlane swaps) ----
        const float g0 = qsum(ag0) + b2[0];
        const float g1 = qsum(ag1) + b2[1];
        const float l0 = qsum(al0) + b3[0];
        const float l1 = qsum(al1) + b3[1];
        const float oo = qsum(aoo) + b4[0];
        const float p00 = qsum(ap00), p01 = qsum(ap01);
        const float p10 = qsum(ap10), p11 = qsum(ap11);
        const float r0 = qsum(ar0),  r1 = qsum(ar1);

        // ---- Tail: 2x2 algebra ----
        const float ld0 = fmaxf(l0, 0.0f);
        const float ld1 = fmaxf(l1, 0.0f);
        const float dr30 = (l0 > 0.0f) ? 1.0f : 0.0f;
        const float dr31 = (l1 > 0.0f) ? 1.0f : 0.0f;

        const float da00 = dr30 * p00, da01 = dr30 * p01;
        const float da10 = dr31 * p10, da11 = dr31 * p11;

        const float l00 = ld0, l10 = oo, l11 = ld1;

        const float m00 = da00 * x2 + da01 * x3;
        const float m11 = da10 * x2 + da11 * x3;
        const float m10 = r0  * x2 + r1  * x3;

        const float eps = 1e-5f;
        const float Hm00 = fmaf(l00, l00, eps);
        const float Hm01 = l00 * l10;
        const float Hm11 = fmaf(l10, l10, fmaf(l11, l11, eps));

        const float dH00 = 2.0f * l00 * m00;
        const float dH01 = fmaf(l00, m10, l10 * m00);
        const float dH11 = 2.0f * fmaf(l10, m10, l11 * m11);

        const float x22 = x2 * x2, x23 = x2 * x3, x33 = x3 * x3;
        const float quad0 = 2.0f * (da00 * l00 * x22
                          + (fmaf(da00, l10, r0 * l00)) * x23
                          + (fmaf(r0, l10, da10 * l11)) * x33);
        const float quad1 = 2.0f * (da01 * l00 * x22
                          + (fmaf(da01, l10, r1 * l00)) * x23
                          + (fmaf(r1, l10, da11 * l11)) * x33);

        const float c0 = fmaf(dH00, x2, dH01 * x3) - 0.5f * quad0;
        const float c1 = fmaf(dH01, x2, dH11 * x3) - 0.5f * quad1;

        const float tau0 = fmaf(Hm00, x4, Hm01 * x5) + c0 + g0;
        const float tau1 = fmaf(Hm01, x4, Hm11 * x5) + c1 + g1;

        // ---- Stores: each qrt quarter writes a different output section ----
        if (s < n_total) {
            const long long N = n_total;
            if (qrt == 0) {
                *((float2*)out + s) = make_float2(tau0, tau1);
            } else if (qrt == 1) {
                *((float4*)(out + 2 * N) + s) = make_float4(Hm00, Hm01, Hm01, Hm11);
            } else if (qrt == 2) {
                *((float2*)(out + 6 * N) + s) = make_float2(c0, c1);
            } else {
                *((float2*)(out + 8 * N) + s) = make_float2(g0, g1);
            }
        }
    }
}

extern "C" void kernel_launch(void* const* d_in, const int* in_sizes, int n_in,
                              void* d_out, int out_size, void* d_ws, size_t ws_size,
                              hipStream_t stream) {
    const float* x   = (const float*)d_in[0];
    const float* W1  = (const float*)d_in[1];
    const float* b1  = (const float*)d_in[2];
    const float* W1a = (const float*)d_in[3];
    const float* b1a = (const float*)d_in[4];
    const float* W2  = (const float*)d_in[5];
    const float* b2  = (const float*)d_in[6];
    const float* W3  = (const float*)d_in[7];
    const float* b3  = (const float*)d_in[8];
    const float* W4  = (const float*)d_in[9];
    const float* b4  = (const float*)d_in[10];
    float* out = (float*)d_out;

    const int n_total = in_sizes[0] / 6;
    const int block = 256;
    const int grid = (n_total + 63) / 64;   // 64 samples per block (16/wave)
    delan_fwd<<<grid, block, 0, stream>>>(x, W1, b1, W1a, b1a, W2, b2,
                                          W3, b3, W4, b4, out, n_total);
}

// Round 9
// 28.101 us; speedup vs baseline: 3.2506x; 3.2506x over previous
//
#include <hip/hip_runtime.h>
#include <stdint.h>

// DeLaN forward, D=2, H1=64. R5-proven core (Phase A + stage-1 MFMA hi/lo,
// absmax 0.0078) with: grid/4 + 4 sequential tiles per block (amortize the
// measured ~5.6us per-block constant build), and the 6 continuous-path
// d-dots (p00..r1) moved to a stage-2 MFMA (f16-hi, A=[W3c0;W3c1;W4] const
// frag, B = d0/d1 repacked via per-wave LDS scratch). Sign-critical dots
// (g0,g1,l0,l1,oo) stay fp32 fma + qsum, bit-identical to R5.

typedef __attribute__((ext_vector_type(8))) _Float16 f16x8;
typedef __attribute__((ext_vector_type(4))) float f32x4;
typedef __attribute__((ext_vector_type(2))) float f32x2;
typedef __attribute__((ext_vector_type(4))) unsigned int u32x4;

#define MFMA16(A,B,C) __builtin_amdgcn_mfma_f32_16x16x32_f16((A),(B),(C),0,0,0)

static __device__ __forceinline__ f32x2 pk_fma(f32x2 a, f32x2 b, f32x2 c) {
    f32x2 d;
    asm("v_pk_fma_f32 %0, %1, %2, %3" : "=v"(d) : "v"(a), "v"(b), "v"(c));
    return d;
}
static __device__ __forceinline__ f32x2 pk_mul(f32x2 a, f32x2 b) {
    f32x2 d;
    asm("v_pk_mul_f32 %0, %1, %2" : "=v"(d) : "v"(a), "v"(b));
    return d;
}
static __device__ __forceinline__ unsigned pkmul16(unsigned a, unsigned b) {
    unsigned d;
    asm("v_pk_mul_f16 %0, %1, %2" : "=v"(d) : "v"(a), "v"(b));
    return d;
}
// sum over lanes {l, l^16, l^32, l^48} (result in every lane), pure VALU
static __device__ __forceinline__ float qsum(float v) {
    float a = v, b = v;
    asm("v_permlane16_swap_b32 %0, %1" : "+v"(a), "+v"(b));
    const float s = a + b;
    float c = s, d = s;
    asm("v_permlane32_swap_b32 %0, %1" : "+v"(c), "+v"(d));
    return c + d;
}

__global__ __launch_bounds__(256, 4) void delan_fwd(
    const float* __restrict__ x,
    const float* __restrict__ W1,  const float* __restrict__ b1,
    const float* __restrict__ W1a, const float* __restrict__ b1a,
    const float* __restrict__ W2,  const float* __restrict__ b2,
    const float* __restrict__ W3,  const float* __restrict__ b3,
    const float* __restrict__ W4,  const float* __restrict__ b4,
    float* __restrict__ out, int n_total)
{
    __shared__ _Float16 afrag[2][4][2][64][8];  // 16 KB stage-1 A frags
    __shared__ float w0s[64], w1s[64], bs[64];  // W1 SoA + b1
    __shared__ float cst[6][64];                // W2c0,W2c1,W3c0,W3c1,W4,b1a
    __shared__ unsigned scr[4][2][576];         // per-wave d0/d1 repack scratch
                                                // idx = p*36 + h/2 (stride 36:
                                                // 16B-aligned b128 reads)

    const int tid  = threadIdx.x;
    const int lane = tid & 63;
    const int wid  = tid >> 6;
    const int p    = lane & 15;
    const int qrt  = lane >> 4;

    // ---- Block-constant build (once per block, amortized over 4 tiles) ----
    if (tid < 64) {
        const int k = tid;
        w0s[k] = W1[2*k]; w1s[k] = W1[2*k+1]; bs[k] = b1[k];
        cst[0][k] = W2[k];      cst[1][k] = W2[64 + k];
        cst[2][k] = W3[k];      cst[3][k] = W3[64 + k];
        cst[4][k] = W4[k];      cst[5][k] = b1a[k];
    }
    {
        const int ht = wid;                 // wave wid builds h-tile wid
#pragma unroll
        for (int kh = 0; kh < 2; ++kh) {
            const int row = ht * 16 + p;
            const int kb  = kh * 32 + qrt * 8;
            float wv[8];
            *(float4*)&wv[0] = *(const float4*)(W1a + row * 64 + kb);
            *(float4*)&wv[4] = *(const float4*)(W1a + row * 64 + kb + 4);
            f16x8 hi, lo;
#pragma unroll
            for (int j = 0; j < 8; ++j) {
                const _Float16 h = (_Float16)wv[j];
                hi[j] = h;
                lo[j] = (_Float16)((wv[j] - (float)h) * 4096.0f);
            }
            *(f16x8*)&afrag[0][ht][kh][lane][0] = hi;
            *(f16x8*)&afrag[1][ht][kh][lane][0] = lo;
        }
    }

    // ---- Stage-2 constant A fragments (registers, f16-hi): rows
    // 0:W3c0, 1:W3c1, 2:W4, 3..15:zero. A row = lane&15, k = qrt*8+j. ----
    f16x8 A2[2];
    {
        const float* arow = (p == 0) ? W3 : (p == 1) ? (W3 + 64) : W4;
#pragma unroll
        for (int kh = 0; kh < 2; ++kh) {
            const int kb = kh * 32 + qrt * 8;
            const float4 aa = *(const float4*)(arow + kb);
            const float4 ab = *(const float4*)(arow + kb + 4);
            f16x8 f;
            f[0] = (_Float16)aa.x; f[1] = (_Float16)aa.y;
            f[2] = (_Float16)aa.z; f[3] = (_Float16)aa.w;
            f[4] = (_Float16)ab.x; f[5] = (_Float16)ab.y;
            f[6] = (_Float16)ab.z; f[7] = (_Float16)ab.w;
            if (p >= 3) {
#pragma unroll
                for (int j = 0; j < 8; ++j) f[j] = (_Float16)0.0f;
            }
            A2[kh] = f;
        }
    }
    __syncthreads();

    const f32x2 c4096  = {4096.0f, 4096.0f};
    const f32x2 cm4096 = {-4096.0f, -4096.0f};
    const long long N  = n_total;

#pragma unroll 1
    for (int t = 0; t < 4; ++t) {
        const int vb = blockIdx.x * 4 + t;
        const int s  = vb * 64 + wid * 16 + p;   // this lane's sample
        const int sc = (s < n_total) ? s : (n_total - 1);

        const float2 xa = *(const float2*)(x + 6 * sc);
        const float2 xb = *(const float2*)(x + 6 * sc + 2);
        const float2 xc = *(const float2*)(x + 6 * sc + 4);
        const float x0 = xa.x, x1 = xa.y;
        const float x2 = xb.x, x3 = xb.y;
        const float x4 = xc.x, x5 = xc.y;

        // ---- Phase A: build B-fragments (packed VALU, R5 verbatim) ----
        const f32x2 q00 = {x0, x0};
        const f32x2 q11 = {x1, x1};
        u32x4 Bhh[2], Bhl[2], Bu0[2], Bu1[2];
#pragma unroll
        for (int kh = 0; kh < 2; ++kh) {
            const int kb = kh * 32 + qrt * 8;
#pragma unroll
            for (int c = 0; c < 4; ++c) {
                const f32x2 w0p = *(const f32x2*)&w0s[kb + 2*c];
                const f32x2 w1p = *(const f32x2*)&w1s[kb + 2*c];
                const f32x2 bp  = *(const f32x2*)&bs [kb + 2*c];
                const f32x2 prep = pk_fma(w0p, q00, pk_fma(w1p, q11, bp));
                const bool pos0 = prep.x > 0.0f;
                const bool pos1 = prep.y > 0.0f;
                const unsigned mlo = pos0 ? 0x00003C00u : 0x0000A11Fu;
                const unsigned mhi = pos1 ? 0x3C000000u : 0xA11F0000u;
                const unsigned drw = mlo | mhi;
                const unsigned p0w = __builtin_bit_cast(unsigned,
                    __builtin_amdgcn_cvt_pkrtz(w0p.x, w0p.y));
                const unsigned p1w = __builtin_bit_cast(unsigned,
                    __builtin_amdgcn_cvt_pkrtz(w1p.x, w1p.y));
                Bu0[kh][c] = pkmul16(p0w, drw);
                Bu1[kh][c] = pkmul16(p1w, drw);
                f32x2 sp;
                sp.x = pos0 ? 1.0f : 0.01f;
                sp.y = pos1 ? 1.0f : 0.01f;
                const f32x2 h1p = pk_mul(prep, sp);
                const auto hhv = __builtin_amdgcn_cvt_pkrtz(h1p.x, h1p.y);
                Bhh[kh][c] = __builtin_bit_cast(unsigned, hhv);
                f32x2 hf;
                hf.x = (float)hhv[0];
                hf.y = (float)hhv[1];
                const f32x2 tt = pk_mul(h1p, c4096);
                const f32x2 rp = pk_fma(hf, cm4096, tt);   // (h1 - hh) * 4096
                Bhl[kh][c] = __builtin_bit_cast(unsigned,
                    __builtin_amdgcn_cvt_pkrtz(rp.x, rp.y));
            }
        }

        // ---- Phase B: stage-1 MFMA + epilogue; d0/d1 -> LDS scratch ----
        float ag0=0.f, ag1=0.f, al0=0.f, al1=0.f, aoo=0.f;
#pragma unroll
        for (int ht = 0; ht < 4; ++ht) {
            const f16x8 Ah0 = *(const f16x8*)&afrag[0][ht][0][lane][0];
            const f16x8 Ah1 = *(const f16x8*)&afrag[0][ht][1][lane][0];
            const f16x8 Al0 = *(const f16x8*)&afrag[1][ht][0][lane][0];
            const f16x8 Al1 = *(const f16x8*)&afrag[1][ht][1][lane][0];
            const f16x8 bh0 = __builtin_bit_cast(f16x8, Bhh[0]);
            const f16x8 bh1 = __builtin_bit_cast(f16x8, Bhh[1]);
            const f16x8 bl0 = __builtin_bit_cast(f16x8, Bhl[0]);
            const f16x8 bl1 = __builtin_bit_cast(f16x8, Bhl[1]);
            const f16x8 bu00 = __builtin_bit_cast(f16x8, Bu0[0]);
            const f16x8 bu01 = __builtin_bit_cast(f16x8, Bu0[1]);
            const f16x8 bu10 = __builtin_bit_cast(f16x8, Bu1[0]);
            const f16x8 bu11 = __builtin_bit_cast(f16x8, Bu1[1]);

            const int hb = ht * 16 + qrt * 4;
            f32x4 Chi = *(const f32x4*)&cst[5][hb];   // init with b1a
            f32x4 Clo = {0.f,0.f,0.f,0.f};
            f32x4 Cz0 = {0.f,0.f,0.f,0.f};
            f32x4 Cz1 = {0.f,0.f,0.f,0.f};
            Chi = MFMA16(Ah0, bh0, Chi);  Chi = MFMA16(Ah1, bh1, Chi);
            Clo = MFMA16(Ah0, bl0, Clo);  Clo = MFMA16(Ah1, bl1, Clo);
            Clo = MFMA16(Al0, bh0, Clo);  Clo = MFMA16(Al1, bh1, Clo);
            Cz0 = MFMA16(Ah0, bu00, Cz0); Cz0 = MFMA16(Ah1, bu01, Cz0);
            Cz1 = MFMA16(Ah0, bu10, Cz1); Cz1 = MFMA16(Ah1, bu11, Cz1);

            const f32x4 w2a  = *(const f32x4*)&cst[0][hb];
            const f32x4 w2b  = *(const f32x4*)&cst[1][hb];
            const f32x4 w3a  = *(const f32x4*)&cst[2][hb];
            const f32x4 w3b  = *(const f32x4*)&cst[3][hb];
            const f32x4 w4v  = *(const f32x4*)&cst[4][hb];
            float d0v[4], d1v[4];
#pragma unroll
            for (int r = 0; r < 4; ++r) {
                const float ah = fmaf(2.44140625e-4f, Clo[r], Chi[r]);
                const bool pos = ah > 0.0f;
                const float h2 = pos ? ah : 0.01f * ah;
                ag0 = fmaf(w2a[r], h2, ag0);   ag1 = fmaf(w2b[r], h2, ag1);
                al0 = fmaf(w3a[r], h2, al0);   al1 = fmaf(w3b[r], h2, al1);
                aoo = fmaf(w4v[r], h2, aoo);
                d0v[r] = pos ? Cz0[r] : -0.01f * Cz0[r];
                d1v[r] = pos ? Cz1[r] : -0.01f * Cz1[r];
            }
            // pack f16 pairs (h even = lo half) and write to scratch:
            // u32 idx = p*36 + h/2, h = ht*16 + qrt*4 + r  -> 8*ht + 2*qrt (+1)
            uint2 pk0, pk1;
            pk0.x = __builtin_bit_cast(unsigned,
                __builtin_amdgcn_cvt_pkrtz(d0v[0], d0v[1]));
            pk0.y = __builtin_bit_cast(unsigned,
                __builtin_amdgcn_cvt_pkrtz(d0v[2], d0v[3]));
            pk1.x = __builtin_bit_cast(unsigned,
                __builtin_amdgcn_cvt_pkrtz(d1v[0], d1v[1]));
            pk1.y = __builtin_bit_cast(unsigned,
                __builtin_amdgcn_cvt_pkrtz(d1v[2], d1v[3]));
            const int iw = p * 36 + 8 * ht + 2 * qrt;
            *(uint2*)&scr[wid][0][iw] = pk0;
            *(uint2*)&scr[wid][1][iw] = pk1;
        }

        // ---- Stage-2 MFMA: 6 d-dots. B col = p (this lane's sample),
        // k = qrt*8+j -> read u32 idx p*36 + 16*kh + 4*qrt (16B aligned). ----
        const int ir = p * 36 + 4 * qrt;
        const f16x8 B00 = *(const f16x8*)&scr[wid][0][ir];
        const f16x8 B01 = *(const f16x8*)&scr[wid][0][ir + 16];
        const f16x8 B10 = *(const f16x8*)&scr[wid][1][ir];
        const f16x8 B11 = *(const f16x8*)&scr[wid][1][ir + 16];
        f32x4 Cd0 = {0.f,0.f,0.f,0.f};
        f32x4 Cd1 = {0.f,0.f,0.f,0.f};
        Cd0 = MFMA16(A2[0], B00, Cd0);  Cd0 = MFMA16(A2[1], B01, Cd0);
        Cd1 = MFMA16(A2[0], B10, Cd1);  Cd1 = MFMA16(A2[1], B11, Cd1);

        // ---- qsum the 5 sign-critical dots (fp32, R5 verbatim) ----
        const float g0 = qsum(ag0) + b2[0];
        const float g1 = qsum(ag1) + b2[1];
        const float l0 = qsum(al0) + b3[0];
        const float l1 = qsum(al1) + b3[1];
        const float oo = qsum(aoo) + b4[0];
        // stage-2 results live on qrt==0 lanes (C rows 0..2):
        const float p00 = Cd0[0], p10 = Cd0[1], r0 = Cd0[2];
        const float p01 = Cd1[0], p11 = Cd1[1], r1 = Cd1[2];

        // ---- Tail: 2x2 algebra (valid on qrt==0; harmless elsewhere) ----
        const float ld0 = fmaxf(l0, 0.0f);
        const float ld1 = fmaxf(l1, 0.0f);
        const float dr30 = (l0 > 0.0f) ? 1.0f : 0.0f;
        const float dr31 = (l1 > 0.0f) ? 1.0f : 0.0f;

        const float da00 = dr30 * p00, da01 = dr30 * p01;
        const float da10 = dr31 * p10, da11 = dr31 * p11;

        const float l00 = ld0, l10 = oo, l11 = ld1;

        const float m00 = da00 * x2 + da01 * x3;
        const float m11 = da10 * x2 + da11 * x3;
        const float m10 = r0  * x2 + r1  * x3;

        const float eps = 1e-5f;
        const float Hm00 = fmaf(l00, l00, eps);
        const float Hm01 = l00 * l10;
        const float Hm11 = fmaf(l10, l10, fmaf(l11, l11, eps));

        const float dH00 = 2.0f * l00 * m00;
        const float dH01 = fmaf(l00, m10, l10 * m00);
        const float dH11 = 2.0f * fmaf(l10, m10, l11 * m11);

        const float x22 = x2 * x2, x23 = x2 * x3, x33 = x3 * x3;
        const float quad0 = 2.0f * (da00 * l00 * x22
                          + (fmaf(da00, l10, r0 * l00)) * x23
                          + (fmaf(r0, l10, da10 * l11)) * x33);
        const float quad1 = 2.0f * (da01 * l00 * x22
                          + (fmaf(da01, l10, r1 * l00)) * x23
                          + (fmaf(r1, l10, da11 * l11)) * x33);

        const float c0 = fmaf(dH00, x2, dH01 * x3) - 0.5f * quad0;
        const float c1 = fmaf(dH01, x2, dH11 * x3) - 0.5f * quad1;

        const float tau0 = fmaf(Hm00, x4, Hm01 * x5) + c0 + g0;
        const float tau1 = fmaf(Hm01, x4, Hm11 * x5) + c1 + g1;

        // ---- Stores: qrt==0 lanes write all 4 sections for their sample ----
        if (s < n_total && qrt == 0) {
            *((float2*)out + s)           = make_float2(tau0, tau1);
            *((float4*)(out + 2 * N) + s) = make_float4(Hm00, Hm01, Hm01, Hm11);
            *((float2*)(out + 6 * N) + s) = make_float2(c0, c1);
            *((float2*)(out + 8 * N) + s) = make_float2(g0, g1);
        }
    }
}

extern "C" void kernel_launch(void* const* d_in, const int* in_sizes, int n_in,
                              void* d_out, int out_size, void* d_ws, size_t ws_size,
                              hipStream_t stream) {
    const float* x   = (const float*)d_in[0];
    const float* W1  = (const float*)d_in[1];
    const float* b1  = (const float*)d_in[2];
    const float* W1a = (const float*)d_in[3];
    const float* b1a = (const float*)d_in[4];
    const float* W2  = (const float*)d_in[5];
    const float* b2  = (const float*)d_in[6];
    const float* W3  = (const float*)d_in[7];
    const float* b3  = (const float*)d_in[8];
    const float* W4  = (const float*)d_in[9];
    const float* b4  = (const float*)d_in[10];
    float* out = (float*)d_out;

    const int n_total = in_sizes[0] / 6;
    const int block = 256;
    const int grid = (n_total + 255) / 256;   // 256 samples/block (4 tiles x 64)
    delan_fwd<<<grid, block, 0, stream>>>(x, W1, b1, W1a, b1a, W2, b2,
                                          W3, b3, W4, b4, out, n_total);
}